// Round 7
// baseline (156.264 us; speedup 1.0000x reference)
//
#include <hip/hip_runtime.h>
#include <hip/hip_fp16.h>
#include <math.h>

typedef _Float16 f16;
typedef _Float16 f16x8 __attribute__((ext_vector_type(8)));
typedef float f32x4 __attribute__((ext_vector_type(4)));
typedef float f32x16 __attribute__((ext_vector_type(16)));
typedef unsigned int u32;
typedef unsigned int u32x4 __attribute__((ext_vector_type(4)));

#define BB 8
#define SS 2048
#define DD 256
#define HH 4
#define DHH 64

#define LOG2E 1.44269504088896340736f
#define MOFF2 (4.0f * LOG2E)          // softmax offset (log2 domain)
#define QSCALE (0.125f * LOG2E)       // 1/sqrt(DH) * log2e, folded into Q store

static __device__ __forceinline__ u32 pkrtz(float a, float b) {
  auto t = __builtin_amdgcn_cvt_pkrtz(a, b);  // __fp16 ext_vector_type(2)
  return __builtin_bit_cast(u32, t);
}

// ---------------------------------------------------------------------------
// Kernel 1: weight pack via LDS transpose tiles (coalesced read AND write).
// ---------------------------------------------------------------------------
__global__ __launch_bounds__(256) void prep_kernel(
    const float* __restrict__ wq, const float* __restrict__ wk,
    const float* __restrict__ wv, const float* __restrict__ wo,
    f16* __restrict__ wqkvT, f16* __restrict__ woT) {
  __shared__ f16 lds[64][72];  // [k_local][dout_local], +8 pad
  int dout0 = blockIdx.x * 64;   // 0..1023
  int k0 = blockIdx.y * 64;      // 0..255
  const float* src;
  f16* dst;
  int col0, drow;
  if (dout0 < 256)      { src = wq; dst = wqkvT; col0 = dout0;       drow = dout0; }
  else if (dout0 < 512) { src = wk; dst = wqkvT; col0 = dout0 - 256; drow = dout0; }
  else if (dout0 < 768) { src = wv; dst = wqkvT; col0 = dout0 - 512; drow = dout0; }
  else                  { src = wo; dst = woT;   col0 = dout0 - 768; drow = dout0 - 768; }

  int dl = threadIdx.x & 63, kl = threadIdx.x >> 6;
#pragma unroll
  for (int i = 0; i < 16; i++) {
    int kloc = i * 4 + kl;
    lds[kloc][dl] = (f16)src[(size_t)(k0 + kloc) * 256 + col0 + dl];
  }
  __syncthreads();
  int row_l = threadIdx.x >> 2, kq = threadIdx.x & 3;
  f16x8 v0, v1;
#pragma unroll
  for (int j = 0; j < 8; j++) v0[j] = lds[kq * 16 + j][row_l];
#pragma unroll
  for (int j = 0; j < 8; j++) v1[j] = lds[kq * 16 + 8 + j][row_l];
  f16* p = dst + (size_t)(drow + row_l) * 256 + k0 + kq * 16;
  *(f16x8*)p = v0;
  *(f16x8*)(p + 8) = v1;
}

// ---------------------------------------------------------------------------
// Kernel 2: fused QKV GEMM, single pass. Grid (256). Each block:
//  - stages its 64x256 x-tile ONCE via coalesced reads (4 thr/row, 1 KB
//    contiguous per row-group) into frag-major astage (f16),
//  - loops 12 n-tiles (Q:0-3, K:4-7, V:8-11) against wqkvT,
//  - Q/K epilogue through lds_t -> f16x8 vector stores (was 16 scalar f16
//    stores/wave/iter); V transposed through lds_t -> V^T rows (unchanged).
// x HBM traffic: 1x (was 3 passes x 4x line-overfetch from row-strided lanes).
// Q pre-scaled by log2e/8 (folds softmax scale+log2 out of attention).
// ---------------------------------------------------------------------------
__global__ __launch_bounds__(256) void qkv_gemm(
    const float* __restrict__ x, const f16* __restrict__ wT,
    f16* __restrict__ Q, f16* __restrict__ K, f16* __restrict__ VT) {
  __shared__ __attribute__((aligned(16))) f16 astage[8][4][64][8];  // 32 KB
  __shared__ __attribute__((aligned(16))) f16 bstage[8][4][64][8];  // 32 KB
  __shared__ __attribute__((aligned(16))) f16 lds_t[64][72];        // 9.2 KB
  int m0 = blockIdx.x * 64;
  int wave = threadIdx.x >> 6, lane = threadIdx.x & 63;
  int lm = lane & 15, quad = lane >> 4;
  int bb = m0 >> 11, s0 = m0 & 2047;

  // ---- coalesced x-tile load -> f16 frag-major astage ----
  {
    int row = threadIdx.x >> 2;          // 0..63
    int c0 = (threadIdx.x & 3) * 64;     // 4 threads cover one 1 KB row
    const float* xr = x + (size_t)(m0 + row) * 256 + c0;
#pragma unroll
    for (int i = 0; i < 8; i++) {
      f32x4 lo = *(const f32x4*)(xr + i * 8);
      f32x4 hi = *(const f32x4*)(xr + i * 8 + 4);
      f16x8 v;
#pragma unroll
      for (int j = 0; j < 4; j++) { v[j] = (f16)lo[j]; v[j + 4] = (f16)hi[j]; }
      int col = c0 + i * 8;
      // astage[kk][w][quad*16+lm][j] = x[w*16+lm][kk*32+quad*8+j]
      *(f16x8*)&astage[col >> 5][row >> 4][((col >> 3) & 3) * 16 + (row & 15)][0] = v;
    }
  }
  __syncthreads();
  f16x8 a[8];
#pragma unroll
  for (int kk = 0; kk < 8; kk++) a[kk] = *(const f16x8*)&astage[kk][wave][lane][0];

  f16x8 breg[8];
  auto bload = [&](int n0) {
#pragma unroll
    for (int kk = 0; kk < 8; kk++)
      breg[kk] = *(const f16x8*)(wT + (size_t)(n0 + wave * 16 + lm) * 256 + kk * 32 + quad * 8);
  };
  bload(0);

  for (int i = 0; i < 12; i++) {
#pragma unroll
    for (int kk = 0; kk < 8; kk++)
      *(f16x8*)&bstage[kk][wave][lane][0] = breg[kk];
    __syncthreads();
    if (i + 1 < 12) bload((i + 1) * 64);

    f32x4 acc[4] = {};
#pragma unroll
    for (int kk = 0; kk < 8; kk++)
#pragma unroll
      for (int nt = 0; nt < 4; nt++) {
        f16x8 b = *(const f16x8*)&bstage[kk][nt][lane][0];
        acc[nt] = __builtin_amdgcn_mfma_f32_16x16x32_f16(a[kk], b, acc[nt], 0, 0, 0);
      }

    int h = i & 3;  // dout = i*64 + nt*16+lm -> h = (i&3) within its matrix, dh = nt*16+lm
    if (i < 8) {
      // Q (i<4) or K (i<8): stage [s_local][dh] then coalesced row stores
      float qsc = (i < 4) ? QSCALE : 1.0f;
#pragma unroll
      for (int nt = 0; nt < 4; nt++)
#pragma unroll
        for (int r = 0; r < 4; r++)
          lds_t[wave * 16 + quad * 4 + r][nt * 16 + lm] = (f16)(acc[nt][r] * qsc);
      __syncthreads();
      int rr = threadIdx.x >> 2, cc = threadIdx.x & 3;
      f16* dst = ((i < 4) ? Q : K) +
                 (((size_t)(bb * HH + h) * SS + s0 + rr) << 6) + cc * 16;
      *(f16x8*)dst = *(const f16x8*)&lds_t[rr][cc * 16];
      *(f16x8*)(dst + 8) = *(const f16x8*)&lds_t[rr][cc * 16 + 8];
    } else {
      // V: transpose tile -> V^T rows
#pragma unroll
      for (int nt = 0; nt < 4; nt++)
#pragma unroll
        for (int r = 0; r < 4; r++)
          lds_t[nt * 16 + lm][wave * 16 + quad * 4 + r] = (f16)acc[nt][r];
      __syncthreads();
      int rr = threadIdx.x >> 2, cc = threadIdx.x & 3;
      f16* vrow = VT + ((size_t)(bb * HH + h) * DHH + rr) * SS + s0;
      *(f16x8*)(vrow + cc * 16) = *(const f16x8*)&lds_t[rr][cc * 16];
      *(f16x8*)(vrow + cc * 16 + 8) = *(const f16x8*)&lds_t[rr][cc * 16 + 8];
    }
    __syncthreads();
  }
}

// ---------------------------------------------------------------------------
// Kernel 3: flash attention (UNCHANGED from round 6 — 53 us known-good).
// Key-split across wave halves; fixed-offset softmax; permlane32_swap builtin.
// ---------------------------------------------------------------------------
__global__ __launch_bounds__(512, 2) void attn_kernel(
    const f16* __restrict__ Q, const f16* __restrict__ K,
    const f16* __restrict__ VT, f16* __restrict__ ctx) {
  // [half][buf][k=0/v=1][frag][lane][8] : 64 KB
  __shared__ __attribute__((aligned(16))) f16 kv[2][2][2][8][64][8];

  int qb = blockIdx.x, hd = blockIdx.y, b = blockIdx.z;
  int w = threadIdx.x >> 6, lane = threadIdx.x & 63;
  int half = w >> 2, wl = w & 3;
  int l31 = lane & 31, hi = lane >> 5, hi8 = hi * 8;
  const f16* Qbh = Q + (size_t)(b * HH + hd) * SS * DHH;
  const f16* Kbh = K + (size_t)(b * HH + hd) * SS * DHH;
  const f16* Vbh = VT + (size_t)(b * HH + hd) * DHH * SS;
  int q0 = qb * 128 + wl * 32;
  int kh0 = half * 1024;

  f16x8 tk0, tk1, tv0, tv1;
  auto stage_load = [&](int key0) {
    tk0 = *(const f16x8*)(Kbh + (size_t)(key0 + l31) * DHH + wl * 16 + hi8);
    tk1 = *(const f16x8*)(Kbh + (size_t)(key0 + 32 + l31) * DHH + wl * 16 + hi8);
    tv0 = *(const f16x8*)(Vbh + (size_t)l31 * SS + key0 + wl * 16 + hi8);
    tv1 = *(const f16x8*)(Vbh + (size_t)(32 + l31) * SS + key0 + wl * 16 + hi8);
  };
  auto stage_write = [&](int buf) {
    *(f16x8*)&kv[half][buf][0][wl][lane][0] = tk0;
    *(f16x8*)&kv[half][buf][0][4 + wl][lane][0] = tk1;
    *(f16x8*)&kv[half][buf][1][wl][lane][0] = tv0;
    *(f16x8*)&kv[half][buf][1][4 + wl][lane][0] = tv1;
  };

  f16x8 aq[4];
  {
    const f16* qrow = Qbh + (size_t)(q0 + l31) * DHH + hi8;
#pragma unroll
    for (int kp = 0; kp < 4; kp++) aq[kp] = *(const f16x8*)(qrow + kp * 16);
  }
  f16x8 vones;
#pragma unroll
  for (int j = 0; j < 8; j++) vones[j] = (f16)1.0f;
  f32x16 minit;
#pragma unroll
  for (int r = 0; r < 16; r++) minit[r] = -MOFF2;

  f32x16 accO0, accO1, accL;
#pragma unroll
  for (int r = 0; r < 16; r++) { accO0[r] = 0.f; accO1[r] = 0.f; accL[r] = 0.f; }

  stage_load(kh0);
  stage_write(0);
  stage_load(kh0 + 64);

  const int NT = 1024 / 64;  // 16 tiles per half
  for (int t = 0; t < NT; t++) {
    int cur = t & 1;
    __syncthreads();

    if (t + 1 < NT) {
      stage_write(cur ^ 1);
      if (t + 2 < NT) stage_load(kh0 + (t + 2) * 64);
    }

    f32x16 accST[2];
#pragma unroll
    for (int kp = 0; kp < 4; kp++)
#pragma unroll
      for (int nt = 0; nt < 2; nt++) {
        f16x8 kf = *(const f16x8*)&kv[half][cur][0][nt * 4 + kp][lane][0];
        accST[nt] = __builtin_amdgcn_mfma_f32_32x32x16_f16(
            kf, aq[kp], kp == 0 ? minit : accST[nt], 0, 0, 0);
      }

    f16x8 pa[4];
#pragma unroll
    for (int nt = 0; nt < 2; nt++) {
      u32 u[4][2];
#pragma unroll
      for (int bq = 0; bq < 4; bq++) {
        float p0 = __builtin_amdgcn_exp2f(accST[nt][4 * bq + 0]);
        float p1 = __builtin_amdgcn_exp2f(accST[nt][4 * bq + 1]);
        float p2 = __builtin_amdgcn_exp2f(accST[nt][4 * bq + 2]);
        float p3 = __builtin_amdgcn_exp2f(accST[nt][4 * bq + 3]);
        u[bq][0] = pkrtz(p0, p1);
        u[bq][1] = pkrtz(p2, p3);
      }
#pragma unroll
      for (int sl = 0; sl < 2; sl++) {
        auto r0 = __builtin_amdgcn_permlane32_swap(u[2 * sl][0], u[2 * sl + 1][0],
                                                   false, false);
        auto r1 = __builtin_amdgcn_permlane32_swap(u[2 * sl][1], u[2 * sl + 1][1],
                                                   false, false);
        u32x4 wv = {(u32)r0[0], (u32)r1[0], (u32)r0[1], (u32)r1[1]};
        pa[nt * 2 + sl] = __builtin_bit_cast(f16x8, wv);
      }
    }

#pragma unroll
    for (int ks = 0; ks < 4; ks++) {
      accL = __builtin_amdgcn_mfma_f32_32x32x16_f16(pa[ks], vones, accL, 0, 0, 0);
      f16x8 v0 = *(const f16x8*)&kv[half][cur][1][ks][lane][0];
      accO0 = __builtin_amdgcn_mfma_f32_32x32x16_f16(pa[ks], v0, accO0, 0, 0, 0);
      f16x8 v1 = *(const f16x8*)&kv[half][cur][1][4 + ks][lane][0];
      accO1 = __builtin_amdgcn_mfma_f32_32x32x16_f16(pa[ks], v1, accO1, 0, 0, 0);
    }
  }

  __syncthreads();
  float* scratch = (float*)kv;
  int sbase = (wl * 64 + lane) * 49;
  if (half == 1) {
#pragma unroll
    for (int r = 0; r < 16; r++) {
      scratch[sbase + r]      = accO0[r];
      scratch[sbase + 16 + r] = accO1[r];
      scratch[sbase + 32 + r] = accL[r];
    }
  }
  __syncthreads();
  if (half == 0) {
#pragma unroll
    for (int r = 0; r < 16; r++) {
      float o0 = accO0[r] + scratch[sbase + r];
      float o1 = accO1[r] + scratch[sbase + 16 + r];
      float rinv = __builtin_amdgcn_rcpf(accL[r] + scratch[sbase + 32 + r]);
      int s = q0 + (r & 3) + 8 * (r >> 2) + 4 * hi;
      f16* dst = ctx + (size_t)(b * SS + s) * DD + hd * DHH + l31;
      dst[0]  = (f16)(o0 * rinv);
      dst[32] = (f16)(o1 * rinv);
    }
  }
}

// ---------------------------------------------------------------------------
// Kernel 4: out = ctx @ W_o + b_o (fp32). Grid (256), 4 n-iters (ctx read
// once). A staged coalesced via astage (was row-strided uncoalesced loads).
// ---------------------------------------------------------------------------
__global__ __launch_bounds__(256) void out_gemm(
    const f16* __restrict__ ctxh, const f16* __restrict__ woT,
    const float* __restrict__ bo, float* __restrict__ out) {
  __shared__ __attribute__((aligned(16))) f16 astage[8][4][64][8];  // 32 KB
  __shared__ __attribute__((aligned(16))) f16 bstage[8][4][64][8];  // 32 KB
  int m0 = blockIdx.x * 64;
  int wave = threadIdx.x >> 6, lane = threadIdx.x & 63;
  int lm = lane & 15, quad = lane >> 4;

  // ---- coalesced ctx-tile load -> frag-major astage ----
  {
    int row = threadIdx.x >> 2;
    int c0 = (threadIdx.x & 3) * 64;
    const f16* cr = ctxh + (size_t)(m0 + row) * 256 + c0;
#pragma unroll
    for (int i = 0; i < 8; i++) {
      f16x8 v = *(const f16x8*)(cr + i * 8);
      int col = c0 + i * 8;
      *(f16x8*)&astage[col >> 5][row >> 4][((col >> 3) & 3) * 16 + (row & 15)][0] = v;
    }
  }
  __syncthreads();
  f16x8 a[8];
#pragma unroll
  for (int kk = 0; kk < 8; kk++) a[kk] = *(const f16x8*)&astage[kk][wave][lane][0];

  f16x8 breg[8];
  auto bload = [&](int n0) {
#pragma unroll
    for (int kk = 0; kk < 8; kk++)
      breg[kk] = *(const f16x8*)(woT + (size_t)(n0 + wave * 16 + lm) * 256 + kk * 32 + quad * 8);
  };
  bload(0);

  for (int i = 0; i < 4; i++) {
    int n0 = i * 64;
#pragma unroll
    for (int kk = 0; kk < 8; kk++)
      *(f16x8*)&bstage[kk][wave][lane][0] = breg[kk];
    __syncthreads();
    if (i + 1 < 4) bload((i + 1) * 64);

    f32x4 acc[4] = {};
#pragma unroll
    for (int kk = 0; kk < 8; kk++)
#pragma unroll
      for (int nt = 0; nt < 4; nt++) {
        f16x8 bfr = *(const f16x8*)&bstage[kk][nt][lane][0];
        acc[nt] = __builtin_amdgcn_mfma_f32_16x16x32_f16(a[kk], bfr, acc[nt], 0, 0, 0);
      }
#pragma unroll
    for (int nt = 0; nt < 4; nt++) {
      int dout = n0 + nt * 16 + lm;
      float bias = bo[dout];
#pragma unroll
      for (int r = 0; r < 4; r++) {
        int t = m0 + wave * 16 + quad * 4 + r;
        out[(size_t)t * 256 + dout] = acc[nt][r] + bias;
      }
    }
    __syncthreads();
  }
}

// ---------------------------------------------------------------------------
extern "C" void kernel_launch(void* const* d_in, const int* in_sizes, int n_in,
                              void* d_out, int out_size, void* d_ws, size_t ws_size,
                              hipStream_t stream) {
  const float* x  = (const float*)d_in[0];
  const float* wq = (const float*)d_in[1];
  const float* wk = (const float*)d_in[2];
  const float* wv = (const float*)d_in[3];
  const float* wo = (const float*)d_in[4];
  const float* bo = (const float*)d_in[5];
  float* out = (float*)d_out;

  char* ws = (char*)d_ws;
  const size_t SZ = 8388608;  // 16384*256*2 bytes
  f16* Qb    = (f16*)(ws);
  f16* Kb    = (f16*)(ws + SZ);
  f16* VTb   = (f16*)(ws + 2 * SZ);
  f16* ctxh  = (f16*)(ws + 3 * SZ);
  f16* wqkvT = (f16*)(ws + 4 * SZ);            // 768*256*2 = 393216
  f16* woT   = (f16*)(ws + 4 * SZ + 393216);   // 256*256*2 = 131072

  hipLaunchKernelGGL(prep_kernel, dim3(16, 4), dim3(256), 0, stream,
                     wq, wk, wv, wo, wqkvT, woT);
  hipLaunchKernelGGL(qkv_gemm, dim3(256), dim3(256), 0, stream,
                     x, wqkvT, Qb, Kb, VTb);
  hipLaunchKernelGGL(attn_kernel, dim3(16, 4, 8), dim3(512), 0, stream,
                     Qb, Kb, VTb, ctxh);
  hipLaunchKernelGGL(out_gemm, dim3(256), dim3(256), 0, stream,
                     ctxh, woT, bo, out);
}